// Round 15
// baseline (801.594 us; speedup 1.0000x reference)
//
#include <hip/hip_runtime.h>
#include <hip/hip_bf16.h>

typedef __attribute__((ext_vector_type(8))) short short8;
typedef __attribute__((ext_vector_type(4))) float f32x4;
using bf16 = __hip_bfloat16;

constexpr int C  = 256;
constexpr int BB = 8;
constexpr int NN = 2048;

#define DEVI __device__ __forceinline__

DEVI short8 ldg8(const bf16* p) { return *reinterpret_cast<const short8*>(p); }

DEVI f32x4 mfma16(short8 a, short8 b, f32x4 c) {
  return __builtin_amdgcn_mfma_f32_16x16x32_bf16(a, b, c, 0, 0, 0);
}

DEVI void split2(float x, bf16& h, bf16& l) {
  h = __float2bfloat16(x);
  l = __float2bfloat16(x - __bfloat162float(h));
}

DEVI short b2s(bf16 x) { short s; __builtin_memcpy(&s, &x, 2); return s; }

// Universal fragment-swizzled layout: FR(n,k,K) = ((n>>4)*(K>>3) + (k>>3))*128
// + (n&15)*8 + (k&7).  MFMA fragment load = 1KB contiguous per wave.

DEVI void store_tile16(const float v[4], bf16* __restrict__ H, bf16* __restrict__ L,
                       size_t tilebase, float* lds, int lane) {
  int l15 = lane & 15, l4 = lane >> 4;
#pragma unroll
  for (int r = 0; r < 4; ++r) lds[(l4 * 4 + r) * 20 + l15] = v[r];
  asm volatile("s_waitcnt lgkmcnt(0)" ::: "memory");
  __builtin_amdgcn_sched_barrier(0);
  int n = lane & 15, cg = (lane >> 4) & 1, pl = lane >> 5;
  short8 o;
#pragma unroll
  for (int j = 0; j < 8; ++j) {
    bf16 h, l;
    split2(lds[n * 20 + cg * 8 + j], h, l);
    o[j] = pl ? b2s(l) : b2s(h);
  }
  bf16* P = pl ? L : H;
  *reinterpret_cast<short8*>(P + tilebase + (size_t)cg * 128 + n * 8) = o;
}

// ---------------- all weights fp32 -> swizzled bf16 hi/lo, ONE launch ----------------
__global__ __launch_bounds__(256) void k_cvtW5(
    const float* __restrict__ s0, const float* __restrict__ s1,
    const float* __restrict__ s2, const float* __restrict__ s3,
    const float* __restrict__ s4, bf16* __restrict__ h0, bf16* __restrict__ l0,
    bf16* __restrict__ h1, bf16* __restrict__ l1, bf16* __restrict__ h2,
    bf16* __restrict__ l2, bf16* __restrict__ h3, bf16* __restrict__ l3,
    bf16* __restrict__ h4, bf16* __restrict__ l4) {
  int idx = blockIdx.x * 256 + threadIdx.x;  // 8-elem chunk id; 90112 total
  const float* s; bf16 *dh, *dl;
  if (idx < 8192)        { s = s0; dh = h0; dl = l0; }
  else if (idx < 16384)  { s = s1; dh = h1; dl = l1; idx -= 8192; }
  else if (idx < 24576)  { s = s2; dh = h2; dl = l2; idx -= 16384; }
  else if (idx < 57344)  { s = s3; dh = h3; dl = l3; idx -= 24576; }
  else                   { s = s4; dh = h4; dl = l4; idx -= 57344; }
  int row = idx >> 5, kg = idx & 31;
  const float* sp = s + row * 256 + kg * 8;
  short8 oh, ol;
#pragma unroll
  for (int j = 0; j < 8; ++j) {
    bf16 h, l;
    split2(sp[j], h, l);
    oh[j] = b2s(h); ol[j] = b2s(l);
  }
  size_t off = ((size_t)(row >> 4) * 32 + kg) * 128 + (row & 15) * 8;
  *reinterpret_cast<short8*>(dh + off) = oh;
  *reinterpret_cast<short8*>(dl + off) = ol;
}

// ---------------- x [B][C][N] f32 -> X' swizzled (rows=n, K=256) hi/lo ----------------
__global__ __launch_bounds__(256) void k_tin(const float* __restrict__ x,
                                             bf16* __restrict__ Xh,
                                             bf16* __restrict__ Xl) {
  __shared__ float tile[64][65];
  int b = blockIdx.z, n0 = blockIdx.x * 64, c0 = blockIdx.y * 64;
  int t = threadIdx.x;
  int tn = t & 63, tq = t >> 6;
#pragma unroll
  for (int i = 0; i < 16; ++i) {
    int cc = i * 4 + tq;
    tile[cc][tn] = x[((size_t)(b * C + c0 + cc)) * NN + n0 + tn];
  }
  __syncthreads();
  bf16* XHb = Xh + (size_t)b * NN * C;
  bf16* XLb = Xl + (size_t)b * NN * C;
#pragma unroll
  for (int i = 0; i < 4; ++i) {
    int e = i * 256 + t;
    int nl = e & 63;
    int cgp = e >> 6;
    int cg = cgp & 7, pl = cgp >> 3;
    short8 o;
#pragma unroll
    for (int j = 0; j < 8; ++j) {
      bf16 h, l;
      split2(tile[cg * 8 + j][nl], h, l);
      o[j] = pl ? b2s(l) : b2s(h);
    }
    int n = n0 + nl;
    size_t off = ((size_t)(n >> 4) * 32 + ((c0 >> 3) + cg)) * 128 + (n & 15) * 8;
    bf16* P = pl ? XLb : XHb;
    *reinterpret_cast<short8*>(P + off) = o;
  }
}

// ------- GEMM: Out[b][n][o] = sum_k A'[b](n,k) W'(o,k) (+bias[o]) -> f32 ------
template <bool BIASJ, bool STATS>
__global__ __launch_bounds__(512, 4) void k_gemm_tr(const bf16* __restrict__ Ah,
                                                    const bf16* __restrict__ Al,
                                                    const bf16* __restrict__ Wh,
                                                    const bf16* __restrict__ Wl,
                                                    const float* __restrict__ bias,
                                                    float* __restrict__ OutF, int OD,
                                                    float* __restrict__ sS,
                                                    float* __restrict__ sS2) {
  __shared__ short8 smW[4096];  // 64KB: hi [0,2048), lo [2048,4096)
  __shared__ float smS[64], smS2[64];
  int b = blockIdx.x, i0 = blockIdx.y * 128, j0 = blockIdx.z * 64;
  int t = threadIdx.x, lane = t & 63, w = t >> 6;
  int l15 = lane & 15, l4 = lane >> 4;
  if (STATS && t < 64) { smS[t] = 0.f; smS2[t] = 0.f; }
  size_t wbase = (size_t)(j0 >> 4) * 4096;
  for (int i = t; i < 2048; i += 512) {
    smW[i]        = ldg8(Wh + wbase + (size_t)i * 8);
    smW[2048 + i] = ldg8(Wl + wbase + (size_t)i * 8);
  }
  __syncthreads();
  const bf16* Abh = Ah + (size_t)b * NN * C;
  const bf16* Abl = Al + (size_t)b * NN * C;
  int ntile = (i0 >> 4) + w;
  f32x4 acc[4];
#pragma unroll
  for (int ct = 0; ct < 4; ++ct) acc[ct] = f32x4{0.f, 0.f, 0.f, 0.f};
#pragma unroll
  for (int ks = 0; ks < 8; ++ks) {
    int ko = ks * 4 + l4;
    short8 a_h = ldg8(Abh + ((size_t)ntile * 32 + ko) * 128 + l15 * 8);
    short8 a_l = ldg8(Abl + ((size_t)ntile * 32 + ko) * 128 + l15 * 8);
#pragma unroll
    for (int ct = 0; ct < 4; ++ct) {
      short8 w_h = smW[ct * 512 + ko * 16 + l15];
      short8 w_l = smW[2048 + ct * 512 + ko * 16 + l15];
      acc[ct] = mfma16(a_h, w_h, acc[ct]);
      acc[ct] = mfma16(a_h, w_l, acc[ct]);
      acc[ct] = mfma16(a_l, w_h, acc[ct]);
    }
  }
#pragma unroll
  for (int ct = 0; ct < 4; ++ct) {
    float bj = 0.f;
    if (BIASJ) bj = bias[j0 + ct * 16 + l15];
    float s = 0.f, s2 = 0.f;
#pragma unroll
    for (int r = 0; r < 4; ++r) {
      float v = acc[ct][r] + bj;
      int row = i0 + w * 16 + l4 * 4 + r;
      OutF[((size_t)(b * NN + row)) * OD + j0 + ct * 16 + l15] = v;
      if (STATS) { s += v; s2 += v * v; }
    }
    if (STATS) {
      s += __shfl_xor(s, 16); s2 += __shfl_xor(s2, 16);
      s += __shfl_xor(s, 32); s2 += __shfl_xor(s2, 32);
      if (l4 == 0) {
        atomicAdd(&smS[ct * 16 + l15], s);
        atomicAdd(&smS2[ct * 16 + l15], s2);
      }
    }
  }
  if (STATS) {
    __syncthreads();
    if (t < 64) {
      atomicAdd(&sS[j0 + t], smS[t]);
      atomicAdd(&sS2[j0 + t], smS2[t]);
    }
  }
}

// ------- q-projection: one 16-row tile per block, wave w = 16-col ct tile -----------
__global__ __launch_bounds__(256) void k_qproj(const bf16* __restrict__ Xh,
                                               const bf16* __restrict__ Xl,
                                               const bf16* __restrict__ Wh,
                                               const bf16* __restrict__ Wl,
                                               bf16* __restrict__ Qh,
                                               bf16* __restrict__ Ql) {
  __shared__ float scratch[4][320];
  int b = blockIdx.x, ntile = blockIdx.y;
  int t = threadIdx.x, lane = t & 63, w = t >> 6;
  int l15 = lane & 15, l4 = lane >> 4;
  const bf16* Abh = Xh + (size_t)b * NN * C;
  const bf16* Abl = Xl + (size_t)b * NN * C;
  f32x4 acc = {0.f, 0.f, 0.f, 0.f};
#pragma unroll
  for (int ks = 0; ks < 8; ++ks) {
    int ko = ks * 4 + l4;
    short8 a_h = ldg8(Abh + ((size_t)ntile * 32 + ko) * 128 + l15 * 8);
    short8 a_l = ldg8(Abl + ((size_t)ntile * 32 + ko) * 128 + l15 * 8);
    size_t wo = ((size_t)w * 32 + ko) * 128 + l15 * 8;
    short8 w_h = ldg8(Wh + wo);
    short8 w_l = ldg8(Wl + wo);
    acc = mfma16(a_h, w_h, acc);
    acc = mfma16(a_h, w_l, acc);
    acc = mfma16(a_l, w_h, acc);
  }
  float v[4] = {acc[0], acc[1], acc[2], acc[3]};
  size_t tb = ((size_t)ntile * 8 + w * 2) * 128;
  store_tile16(v, Qh + (size_t)b * NN * 64, Ql + (size_t)b * NN * 64, tb,
               scratch[w], lane);
}

// ------- V'[b](c,m) = sum_k W'(c,k) X'[b](m,k) + bias[c]; X-tile LDS-staged ---------
__global__ __launch_bounds__(512, 4) void k_gemm_nm(const bf16* __restrict__ Wh,
                                                    const bf16* __restrict__ Wl,
                                                    const bf16* __restrict__ Xh,
                                                    const bf16* __restrict__ Xl,
                                                    const float* __restrict__ bias,
                                                    bf16* __restrict__ Vh,
                                                    bf16* __restrict__ Vl) {
  __shared__ short8 smX[4096];  // 64KB: hi [0,2048), lo [2048,4096)
  __shared__ float scratch[8][320];
  int b = blockIdx.x, i0 = blockIdx.y * 128, j0 = blockIdx.z * 64;
  int t = threadIdx.x, lane = t & 63, w = t >> 6;
  int l15 = lane & 15, l4 = lane >> 4;
  const bf16* Xbh = Xh + (size_t)b * NN * C;
  const bf16* Xbl = Xl + (size_t)b * NN * C;
  size_t xbase = (size_t)(j0 >> 4) * 4096;
  for (int i = t; i < 2048; i += 512) {
    smX[i]        = ldg8(Xbh + xbase + (size_t)i * 8);
    smX[2048 + i] = ldg8(Xbl + xbase + (size_t)i * 8);
  }
  __syncthreads();
  int ntile = (i0 >> 4) + w;
  f32x4 acc[4];
#pragma unroll
  for (int ct = 0; ct < 4; ++ct) acc[ct] = f32x4{0.f, 0.f, 0.f, 0.f};
#pragma unroll
  for (int ks = 0; ks < 8; ++ks) {
    int ko = ks * 4 + l4;
    short8 a_h = ldg8(Wh + ((size_t)ntile * 32 + ko) * 128 + l15 * 8);
    short8 a_l = ldg8(Wl + ((size_t)ntile * 32 + ko) * 128 + l15 * 8);
#pragma unroll
    for (int ct = 0; ct < 4; ++ct) {
      short8 x_h = smX[ct * 512 + ko * 16 + l15];
      short8 x_l = smX[2048 + ct * 512 + ko * 16 + l15];
      acc[ct] = mfma16(a_h, x_h, acc[ct]);
      acc[ct] = mfma16(a_h, x_l, acc[ct]);
      acc[ct] = mfma16(a_l, x_h, acc[ct]);
    }
  }
  float br[4];
#pragma unroll
  for (int r = 0; r < 4; ++r) br[r] = bias[i0 + w * 16 + l4 * 4 + r];
  bf16* Vbh = Vh + (size_t)b * C * NN;
  bf16* Vbl = Vl + (size_t)b * C * NN;
#pragma unroll
  for (int ct = 0; ct < 4; ++ct) {
    float v[4];
#pragma unroll
    for (int r = 0; r < 4; ++r) v[r] = acc[ct][r] + br[r];
    size_t tb = ((size_t)ntile * (NN >> 3) + ((j0 + ct * 16) >> 3)) * 128;
    store_tile16(v, Vbh, Vbl, tb, scratch[w], lane);
  }
}

// ---------- row softmax stats over E = Q Q^T (online, 2x-unrolled, exact) ----------
__global__ __launch_bounds__(256) void k_rowstats(const bf16* __restrict__ Qh,
                                                  const bf16* __restrict__ Ql,
                                                  float* __restrict__ rm,
                                                  float* __restrict__ irs) {
  __shared__ float redM[4][16], redS[4][16];
  int b = blockIdx.x;
  int t = threadIdx.x, lane = t & 63, w = t >> 6;
  int l15 = lane & 15, l4 = lane >> 4;
  int mt = blockIdx.y;
  const bf16* QHb = Qh + (size_t)b * NN * 64;
  const bf16* QLb = Ql + (size_t)b * NN * 64;
  short8 ah0 = ldg8(QHb + ((size_t)mt * 8 + l4) * 128 + l15 * 8);
  short8 ah1 = ldg8(QHb + ((size_t)mt * 8 + 4 + l4) * 128 + l15 * 8);
  short8 al0 = ldg8(QLb + ((size_t)mt * 8 + l4) * 128 + l15 * 8);
  short8 al1 = ldg8(QLb + ((size_t)mt * 8 + 4 + l4) * 128 + l15 * 8);
  float lmax[4], lsum[4];
#pragma unroll
  for (int r = 0; r < 4; ++r) { lmax[r] = -3.4e38f; lsum[r] = 0.f; }
  for (int nb = w * 32; nb < w * 32 + 32; nb += 2) {
    short8 bh0 = ldg8(QHb + ((size_t)nb * 8 + l4) * 128 + l15 * 8);
    short8 bh1 = ldg8(QHb + ((size_t)nb * 8 + 4 + l4) * 128 + l15 * 8);
    short8 bl0 = ldg8(QLb + ((size_t)nb * 8 + l4) * 128 + l15 * 8);
    short8 bl1 = ldg8(QLb + ((size_t)nb * 8 + 4 + l4) * 128 + l15 * 8);
    short8 ch0 = ldg8(QHb + ((size_t)(nb + 1) * 8 + l4) * 128 + l15 * 8);
    short8 ch1 = ldg8(QHb + ((size_t)(nb + 1) * 8 + 4 + l4) * 128 + l15 * 8);
    short8 cl0 = ldg8(QLb + ((size_t)(nb + 1) * 8 + l4) * 128 + l15 * 8);
    short8 cl1 = ldg8(QLb + ((size_t)(nb + 1) * 8 + 4 + l4) * 128 + l15 * 8);
    f32x4 e1 = {0.f, 0.f, 0.f, 0.f}, e2 = {0.f, 0.f, 0.f, 0.f};
    e1 = mfma16(ah0, bh0, e1); e1 = mfma16(ah1, bh1, e1);
    e1 = mfma16(ah0, bl0, e1); e1 = mfma16(ah1, bl1, e1);
    e1 = mfma16(al0, bh0, e1); e1 = mfma16(al1, bh1, e1);
    e2 = mfma16(ah0, ch0, e2); e2 = mfma16(ah1, ch1, e2);
    e2 = mfma16(ah0, cl0, e2); e2 = mfma16(ah1, cl1, e2);
    e2 = mfma16(al0, ch0, e2); e2 = mfma16(al1, ch1, e2);
#pragma unroll
    for (int r = 0; r < 4; ++r) {
      float nm = fmaxf(lmax[r], fmaxf(e1[r], e2[r]));
      lsum[r] = lsum[r] * __expf(lmax[r] - nm) + __expf(e1[r] - nm) + __expf(e2[r] - nm);
      lmax[r] = nm;
    }
  }
#pragma unroll
  for (int r = 0; r < 4; ++r) {
    for (int mk = 1; mk < 16; mk <<= 1) {
      float om = __shfl_xor(lmax[r], mk, 16);
      float os = __shfl_xor(lsum[r], mk, 16);
      float nm = fmaxf(lmax[r], om);
      lsum[r] = lsum[r] * __expf(lmax[r] - nm) + os * __expf(om - nm);
      lmax[r] = nm;
    }
  }
  if (l15 == 0) {
#pragma unroll
    for (int r = 0; r < 4; ++r) {
      redM[w][l4 * 4 + r] = lmax[r];
      redS[w][l4 * 4 + r] = lsum[r];
    }
  }
  __syncthreads();
  if (t < 16) {
    float m = redM[0][t];
    m = fmaxf(m, redM[1][t]); m = fmaxf(m, redM[2][t]); m = fmaxf(m, redM[3][t]);
    float s = 0.f;
#pragma unroll
    for (int w2 = 0; w2 < 4; ++w2) s += redS[w2][t] * __expf(redM[w2][t] - m);
    rm[b * NN + mt * 16 + t] = m;
    irs[b * NN + mt * 16 + t] = 1.0f / s;
  }
}

// ---------------- fused attention: D' = X - (V att)/(1e-9+colsum), swizzled out ------
// 256-m steps: barriers 16->8. PV = 8-kc pipeline w/ 1-ahead V prefetch (32 live
// V regs). bounds(512,2): VGPR cap 128 (grid 512 = 2 blk/CU -> no occ loss; avoids
// R13's spill-at-64 trap). V hi/lo (R11). NO setprio (R9).
__global__ __launch_bounds__(512, 2) void k_attnY(const bf16* __restrict__ QH,
                                                  const bf16* __restrict__ QL,
                                                  const bf16* __restrict__ VH,
                                                  const bf16* __restrict__ VL,
                                                  const float* __restrict__ rm,
                                                  const float* __restrict__ irs,
                                                  const bf16* __restrict__ XH,
                                                  const bf16* __restrict__ XL,
                                                  bf16* __restrict__ DH,
                                                  bf16* __restrict__ DL) {
  __shared__ bf16 Pb[2][64 * 136];
  __shared__ float rmL[2048], irL[2048];
  __shared__ float colLds[32];
  __shared__ float scratch[8][320];
  int bid = blockIdx.x;
  int b = bid & 7, n0 = (bid >> 3) * 32;
  int t = threadIdx.x, lane = t & 63, w = t >> 6;
  int l15 = lane & 15, l4 = lane >> 4;
  int nt = w >> 2, pp = w & 3;
  const bf16* QHb = QH + (size_t)b * NN * 64;
  const bf16* QLb = QL + (size_t)b * NN * 64;
  const bf16* VHb = VH + (size_t)b * C * NN;
  const bf16* VLb = VL + (size_t)b * C * NN;
  for (int i = t; i < NN; i += 512) {
    rmL[i] = rm[b * NN + i];
    irL[i] = irs[b * NN + i];
  }
  if (t < 32) colLds[t] = 0.f;
  int ntq = (n0 >> 4) + nt;
  short8 qh0 = ldg8(QHb + ((size_t)ntq * 8 + l4) * 128 + l15 * 8);
  short8 qh1 = ldg8(QHb + ((size_t)ntq * 8 + 4 + l4) * 128 + l15 * 8);
  short8 ql0 = ldg8(QLb + ((size_t)ntq * 8 + l4) * 128 + l15 * 8);
  short8 ql1 = ldg8(QLb + ((size_t)ntq * 8 + 4 + l4) * 128 + l15 * 8);
  f32x4 zero = {0.f, 0.f, 0.f, 0.f};
  f32x4 acc[2][2];
#pragma unroll
  for (int a = 0; a < 2; ++a)
#pragma unroll
    for (int ct = 0; ct < 2; ++ct) acc[a][ct] = zero;
  float cac[4] = {0.f, 0.f, 0.f, 0.f};
  __syncthreads();
  for (int s = 0; s < 8; ++s) {
    bf16* pbw = Pb[s & 1];
    // ---- E phase: four 16x16 tiles (m-tiles pp*4..pp*4+3 of this 256-m step) ----
#pragma unroll
    for (int sub = 0; sub < 4; ++sub) {
      int mt16 = pp * 4 + sub;
      int gmt = s * 16 + mt16;
      short8 bh0 = ldg8(QHb + ((size_t)gmt * 8 + l4) * 128 + l15 * 8);
      short8 bh1 = ldg8(QHb + ((size_t)gmt * 8 + 4 + l4) * 128 + l15 * 8);
      short8 bl0 = ldg8(QLb + ((size_t)gmt * 8 + l4) * 128 + l15 * 8);
      short8 bl1 = ldg8(QLb + ((size_t)gmt * 8 + 4 + l4) * 128 + l15 * 8);
      f32x4 eA = zero, eB = zero;
      eA = mfma16(qh0, bh0, eA); eB = mfma16(qh1, bh1, eB);
      eA = mfma16(qh0, bl0, eA); eB = mfma16(qh1, bl1, eB);
      eA = mfma16(ql0, bh0, eA); eB = mfma16(ql1, bh1, eB);
      float rmv = rmL[gmt * 16 + l15], iv = irL[gmt * 16 + l15];
      int blk = nt * 32 + mt16 * 2 + (l15 >> 3);
#pragma unroll
      for (int r = 0; r < 4; ++r) {
        float p = __expf(eA[r] + eB[r] - rmv) * iv;
        bf16 ph = __float2bfloat16(p);
        cac[r] += __bfloat162float(ph);
        pbw[blk * 136 + (l4 * 4 + r) * 8 + (l15 & 7)] = ph;
      }
    }
    // ---- prefetch V kc=0 (stays in flight across raw barrier) ----
    short8 vch[2], vcl[2], vnh[2], vnl[2];
#pragma unroll
    for (int ct = 0; ct < 2; ++ct) {
      size_t vo = ((size_t)(w * 2 + ct) * 256 + s * 32 + l4) * 128 + l15 * 8;
      vch[ct] = ldg8(VHb + vo);
      vcl[ct] = ldg8(VLb + vo);
    }
    asm volatile("s_waitcnt lgkmcnt(0)" ::: "memory");
    __builtin_amdgcn_sched_barrier(0);
    __builtin_amdgcn_s_barrier();
    // ---- PV: 8 kc-chunks, 1-ahead pipeline ----
#pragma unroll
    for (int kc = 0; kc < 8; ++kc) {
      if (kc < 7) {
#pragma unroll
        for (int ct = 0; ct < 2; ++ct) {
          size_t vo = ((size_t)(w * 2 + ct) * 256 + s * 32 + (kc + 1) * 4 + l4) * 128 + l15 * 8;
          vnh[ct] = ldg8(VHb + vo);
          vnl[ct] = ldg8(VLb + vo);
        }
      }
      short8 pa0 = *reinterpret_cast<const short8*>(&pbw[(kc * 4 + l4) * 136 + l15 * 8]);
      short8 pa1 = *reinterpret_cast<const short8*>(&pbw[((32 + kc * 4 + l4)) * 136 + l15 * 8]);
#pragma unroll
      for (int ct = 0; ct < 2; ++ct) {
        acc[0][ct] = mfma16(pa0, vch[ct], acc[0][ct]);
        acc[0][ct] = mfma16(pa0, vcl[ct], acc[0][ct]);
        acc[1][ct] = mfma16(pa1, vch[ct], acc[1][ct]);
        acc[1][ct] = mfma16(pa1, vcl[ct], acc[1][ct]);
      }
#pragma unroll
      for (int ct = 0; ct < 2; ++ct) { vch[ct] = vnh[ct]; vcl[ct] = vnl[ct]; }
    }
  }
  // colsum: reduce over 16 m-lanes; 4 p-waves per nt combine via LDS atomics
#pragma unroll
  for (int r = 0; r < 4; ++r) {
    float v2 = cac[r];
    v2 += __shfl_xor(v2, 1, 16); v2 += __shfl_xor(v2, 2, 16);
    v2 += __shfl_xor(v2, 4, 16); v2 += __shfl_xor(v2, 8, 16);
    if (l15 == 0) atomicAdd(&colLds[nt * 16 + l4 * 4 + r], v2);
  }
  __syncthreads();
  if (t < 32) colLds[t] = 1.0f / (1e-9f + colLds[t]);
  __syncthreads();
  const bf16* XHb = XH + (size_t)b * NN * C;
  const bf16* XLb = XL + (size_t)b * NN * C;
  bf16* DHb = DH + (size_t)b * NN * C;
  bf16* DLb = DL + (size_t)b * NN * C;
#pragma unroll
  for (int a = 0; a < 2; ++a) {
#pragma unroll
    for (int ct = 0; ct < 2; ++ct) {
      float d[4];
      int cidx = w * 32 + ct * 16 + l15;
#pragma unroll
      for (int r = 0; r < 4; ++r) {
        int n = n0 + a * 16 + l4 * 4 + r;
        size_t off = ((size_t)(n >> 4) * 32 + (cidx >> 3)) * 128 + (n & 15) * 8 + (cidx & 7);
        float xv = __bfloat162float(XHb[off]) + __bfloat162float(XLb[off]);
        d[r] = xv - acc[a][ct][r] * colLds[a * 16 + l4 * 4 + r];
      }
      size_t tb = ((size_t)((n0 >> 4) + a) * 32 + ((w * 32 + ct * 16) >> 3)) * 128;
      store_tile16(d, DHb, DLb, tb, scratch[w], lane);
    }
  }
}

// -------- BN + ReLU (+ residual + out); x canonical as hi/lo pair --------
template <bool RES>
__global__ __launch_bounds__(256) void k_bnrelu(const float* __restrict__ Tt,
                                                const float* __restrict__ sS,
                                                const float* __restrict__ sS2,
                                                const float* __restrict__ g,
                                                const float* __restrict__ bb,
                                                bf16* __restrict__ Xh,
                                                bf16* __restrict__ Xl,
                                                float* __restrict__ outp, int Loff) {
  __shared__ float vb[16][257];
  int b = blockIdx.x, n0 = blockIdx.y * 16;
  int c = threadIdx.x;
  float cnt = (float)(BB * NN);
  float mean = sS[c] / cnt;
  float var = fmaxf(sS2[c] / cnt - mean * mean, 0.f);
  float sc = g[c] * rsqrtf(var + 1e-5f);
  float sh = bb[c] - mean * sc;
#pragma unroll
  for (int i = 0; i < 16; ++i) {
    int n = n0 + i;
    size_t idx = ((size_t)(b * NN + n)) * C + c;
    float v = Tt[idx] * sc + sh;
    v = fmaxf(v, 0.f);
    size_t off = (size_t)b * NN * C +
                 ((size_t)(n >> 4) * 32 + (c >> 3)) * 128 + (n & 15) * 8 + (c & 7);
    if (RES) v += __bfloat162float(Xh[off]) + __bfloat162float(Xl[off]);
    bf16 h, l;
    split2(v, h, l);
    Xh[off] = h;
    Xl[off] = l;
    if (RES) vb[i][c] = v;
  }
  if (RES) {
    __syncthreads();
    int nl = threadIdx.x & 15, cb = threadIdx.x >> 4;
#pragma unroll
    for (int j = 0; j < 16; ++j) {
      int cc = cb + j * 16;
      outp[((size_t)(b * 1024 + Loff + cc)) * NN + n0 + nl] = vb[nl][cc];
    }
  }
}

extern "C" void kernel_launch(void* const* d_in, const int* in_sizes, int n_in,
                              void* d_out, int out_size, void* d_ws, size_t ws_size,
                              hipStream_t stream) {
  const float* x       = (const float*)d_in[0];
  const float* conv1_w = (const float*)d_in[1];
  const float* conv2_w = (const float*)d_in[2];
  const float* bn1_g   = (const float*)d_in[3];
  const float* bn1_b   = (const float*)d_in[4];
  const float* bn2_g   = (const float*)d_in[5];
  const float* bn2_b   = (const float*)d_in[6];
  const float* wqk     = (const float*)d_in[7];
  const float* wv      = (const float*)d_in[8];
  const float* bv      = (const float*)d_in[9];
  const float* wt      = (const float*)d_in[10];
  const float* bt      = (const float*)d_in[11];
  const float* sg      = (const float*)d_in[12];
  const float* sb      = (const float*)d_in[13];
  float* out = (float*)d_out;

  char* p = (char*)d_ws;
  auto take = [&](size_t n) { char* r = p; p += n; return r; };
  bf16* WB1h = (bf16*)take(131072);
  bf16* WB1l = (bf16*)take(131072);
  bf16* WB2h = (bf16*)take(131072);
  bf16* WB2l = (bf16*)take(131072);
  bf16* WBQh = (bf16*)take(131072);
  bf16* WBQl = (bf16*)take(131072);
  bf16* WBVh = (bf16*)take(524288);
  bf16* WBVl = (bf16*)take(524288);
  bf16* WBTh = (bf16*)take(524288);
  bf16* WBTl = (bf16*)take(524288);
  bf16* XTh  = (bf16*)take(8388608);
  bf16* XTl  = (bf16*)take(8388608);
  bf16* QTh  = (bf16*)take(2097152);
  bf16* QTl  = (bf16*)take(2097152);
  bf16* VBh  = (bf16*)take(8388608);
  bf16* VBl  = (bf16*)take(8388608);
  float* TT  = (float*)VBh;  // alias: t-GEMM output written after attnY consumed V
  bf16* DTh  = (bf16*)take(8388608);
  bf16* DTl  = (bf16*)take(8388608);
  float* RM   = (float*)take(65536);
  float* IRS  = (float*)take(65536);
  float* STAT = (float*)take(12288);

  hipMemsetAsync(STAT, 0, 6 * 512 * sizeof(float), stream);
  k_cvtW5<<<352, 256, 0, stream>>>(conv1_w, conv2_w, wqk, wv, wt,
                                   WB1h, WB1l, WB2h, WB2l, WBQh, WBQl,
                                   WBVh, WBVl, WBTh, WBTl);
  k_tin<<<dim3(32, 4, 8), 256, 0, stream>>>(x, XTh, XTl);

  // conv1 + bn1 + relu   (TT aliases VB, safe — V not yet used)
  k_gemm_tr<false, true><<<dim3(8, 16, 4), 512, 0, stream>>>(
      XTh, XTl, WB1h, WB1l, nullptr, TT, 256, STAT + 0, STAT + 256);
  k_bnrelu<false><<<dim3(8, 128), 256, 0, stream>>>(TT, STAT + 0, STAT + 256, bn1_g, bn1_b,
                                                    XTh, XTl, nullptr, 0);

  // conv2 + bn2 + relu
  k_gemm_tr<false, true><<<dim3(8, 16, 4), 512, 0, stream>>>(
      XTh, XTl, WB2h, WB2l, nullptr, TT, 256, STAT + 512, STAT + 768);
  k_bnrelu<false><<<dim3(8, 128), 256, 0, stream>>>(TT, STAT + 512, STAT + 768, bn2_g, bn2_b,
                                                    XTh, XTl, nullptr, 0);

  for (int L = 0; L < 4; ++L) {
    float* ST = STAT + (2 + L) * 512;
    // q projection -> Q' swizzled [B], rows=N, K=64
    k_qproj<<<dim3(8, 128), 256, 0, stream>>>(XTh, XTl, WBQh + L * 16384,
                                              WBQl + L * 16384, QTh, QTl);
    // v projection -> V' swizzled [B], rows=C, K=N (hi+lo; X-tile LDS-staged)
    k_gemm_nm<<<dim3(8, 2, 32), 512, 0, stream>>>(WBVh + L * 65536, WBVl + L * 65536,
                                                  XTh, XTl, bv + L * 256, VBh, VBl);
    // softmax row stats (online, 2x-unrolled)
    k_rowstats<<<dim3(8, 128), 256, 0, stream>>>(QTh, QTl, RM, IRS);
    // fused E + softmax (P once) + renorm + V-apply + subtract -> D' swizzled
    k_attnY<<<512, 512, 0, stream>>>(QTh, QTl, VBh, VBl, RM, IRS, XTh, XTl, DTh, DTl);
    // t projection + stats (TT aliases VB — V fully consumed by attnY above)
    k_gemm_tr<true, true><<<dim3(8, 16, 4), 512, 0, stream>>>(
        DTh, DTl, WBTh + L * 65536, WBTl + L * 65536, bt + L * 256, TT, 256, ST, ST + 256);
    // bn + relu + residual + output slice (bnfin fused)
    k_bnrelu<true><<<dim3(8, 128), 256, 0, stream>>>(TT, ST, ST + 256, sg + L * 256,
                                                     sb + L * 256, XTh, XTl, out,
                                                     L * 256);
  }
}

// Round 16
// 623.717 us; speedup vs baseline: 1.2852x; 1.2852x over previous
//
#include <hip/hip_runtime.h>
#include <hip/hip_bf16.h>

typedef __attribute__((ext_vector_type(8))) short short8;
typedef __attribute__((ext_vector_type(4))) float f32x4;
using bf16 = __hip_bfloat16;

constexpr int C  = 256;
constexpr int BB = 8;
constexpr int NN = 2048;

#define DEVI __device__ __forceinline__

DEVI short8 ldg8(const bf16* p) { return *reinterpret_cast<const short8*>(p); }

DEVI f32x4 mfma16(short8 a, short8 b, f32x4 c) {
  return __builtin_amdgcn_mfma_f32_16x16x32_bf16(a, b, c, 0, 0, 0);
}

DEVI void split2(float x, bf16& h, bf16& l) {
  h = __float2bfloat16(x);
  l = __float2bfloat16(x - __bfloat162float(h));
}

DEVI short b2s(bf16 x) { short s; __builtin_memcpy(&s, &x, 2); return s; }

// Universal fragment-swizzled layout: FR(n,k,K) = ((n>>4)*(K>>3) + (k>>3))*128
// + (n&15)*8 + (k&7).  MFMA fragment load = 1KB contiguous per wave.

DEVI void store_tile16(const float v[4], bf16* __restrict__ H, bf16* __restrict__ L,
                       size_t tilebase, float* lds, int lane) {
  int l15 = lane & 15, l4 = lane >> 4;
#pragma unroll
  for (int r = 0; r < 4; ++r) lds[(l4 * 4 + r) * 20 + l15] = v[r];
  asm volatile("s_waitcnt lgkmcnt(0)" ::: "memory");
  __builtin_amdgcn_sched_barrier(0);
  int n = lane & 15, cg = (lane >> 4) & 1, pl = lane >> 5;
  short8 o;
#pragma unroll
  for (int j = 0; j < 8; ++j) {
    bf16 h, l;
    split2(lds[n * 20 + cg * 8 + j], h, l);
    o[j] = pl ? b2s(l) : b2s(h);
  }
  bf16* P = pl ? L : H;
  *reinterpret_cast<short8*>(P + tilebase + (size_t)cg * 128 + n * 8) = o;
}

// ---------------- all weights fp32 -> swizzled bf16 hi/lo, ONE launch ----------------
__global__ __launch_bounds__(256) void k_cvtW5(
    const float* __restrict__ s0, const float* __restrict__ s1,
    const float* __restrict__ s2, const float* __restrict__ s3,
    const float* __restrict__ s4, bf16* __restrict__ h0, bf16* __restrict__ l0,
    bf16* __restrict__ h1, bf16* __restrict__ l1, bf16* __restrict__ h2,
    bf16* __restrict__ l2, bf16* __restrict__ h3, bf16* __restrict__ l3,
    bf16* __restrict__ h4, bf16* __restrict__ l4) {
  int idx = blockIdx.x * 256 + threadIdx.x;  // 8-elem chunk id; 90112 total
  const float* s; bf16 *dh, *dl;
  if (idx < 8192)        { s = s0; dh = h0; dl = l0; }
  else if (idx < 16384)  { s = s1; dh = h1; dl = l1; idx -= 8192; }
  else if (idx < 24576)  { s = s2; dh = h2; dl = l2; idx -= 16384; }
  else if (idx < 57344)  { s = s3; dh = h3; dl = l3; idx -= 24576; }
  else                   { s = s4; dh = h4; dl = l4; idx -= 57344; }
  int row = idx >> 5, kg = idx & 31;
  const float* sp = s + row * 256 + kg * 8;
  short8 oh, ol;
#pragma unroll
  for (int j = 0; j < 8; ++j) {
    bf16 h, l;
    split2(sp[j], h, l);
    oh[j] = b2s(h); ol[j] = b2s(l);
  }
  size_t off = ((size_t)(row >> 4) * 32 + kg) * 128 + (row & 15) * 8;
  *reinterpret_cast<short8*>(dh + off) = oh;
  *reinterpret_cast<short8*>(dl + off) = ol;
}

// ---------------- x [B][C][N] f32 -> X' swizzled (rows=n, K=256) hi/lo ----------------
__global__ __launch_bounds__(256) void k_tin(const float* __restrict__ x,
                                             bf16* __restrict__ Xh,
                                             bf16* __restrict__ Xl) {
  __shared__ float tile[64][65];
  int b = blockIdx.z, n0 = blockIdx.x * 64, c0 = blockIdx.y * 64;
  int t = threadIdx.x;
  int tn = t & 63, tq = t >> 6;
#pragma unroll
  for (int i = 0; i < 16; ++i) {
    int cc = i * 4 + tq;
    tile[cc][tn] = x[((size_t)(b * C + c0 + cc)) * NN + n0 + tn];
  }
  __syncthreads();
  bf16* XHb = Xh + (size_t)b * NN * C;
  bf16* XLb = Xl + (size_t)b * NN * C;
#pragma unroll
  for (int i = 0; i < 4; ++i) {
    int e = i * 256 + t;
    int nl = e & 63;
    int cgp = e >> 6;
    int cg = cgp & 7, pl = cgp >> 3;
    short8 o;
#pragma unroll
    for (int j = 0; j < 8; ++j) {
      bf16 h, l;
      split2(tile[cg * 8 + j][nl], h, l);
      o[j] = pl ? b2s(l) : b2s(h);
    }
    int n = n0 + nl;
    size_t off = ((size_t)(n >> 4) * 32 + ((c0 >> 3) + cg)) * 128 + (n & 15) * 8;
    bf16* P = pl ? XLb : XHb;
    *reinterpret_cast<short8*>(P + off) = o;
  }
}

// ------- GEMM: Out[b][n][o] = sum_k A'[b](n,k) W'(o,k) (+bias[o]) -> f32 ------
template <bool BIASJ, bool STATS>
__global__ __launch_bounds__(512, 4) void k_gemm_tr(const bf16* __restrict__ Ah,
                                                    const bf16* __restrict__ Al,
                                                    const bf16* __restrict__ Wh,
                                                    const bf16* __restrict__ Wl,
                                                    const float* __restrict__ bias,
                                                    float* __restrict__ OutF, int OD,
                                                    float* __restrict__ sS,
                                                    float* __restrict__ sS2) {
  __shared__ short8 smW[4096];  // 64KB: hi [0,2048), lo [2048,4096)
  __shared__ float smS[64], smS2[64];
  int b = blockIdx.x, i0 = blockIdx.y * 128, j0 = blockIdx.z * 64;
  int t = threadIdx.x, lane = t & 63, w = t >> 6;
  int l15 = lane & 15, l4 = lane >> 4;
  if (STATS && t < 64) { smS[t] = 0.f; smS2[t] = 0.f; }
  size_t wbase = (size_t)(j0 >> 4) * 4096;
  for (int i = t; i < 2048; i += 512) {
    smW[i]        = ldg8(Wh + wbase + (size_t)i * 8);
    smW[2048 + i] = ldg8(Wl + wbase + (size_t)i * 8);
  }
  __syncthreads();
  const bf16* Abh = Ah + (size_t)b * NN * C;
  const bf16* Abl = Al + (size_t)b * NN * C;
  int ntile = (i0 >> 4) + w;
  f32x4 acc[4];
#pragma unroll
  for (int ct = 0; ct < 4; ++ct) acc[ct] = f32x4{0.f, 0.f, 0.f, 0.f};
#pragma unroll
  for (int ks = 0; ks < 8; ++ks) {
    int ko = ks * 4 + l4;
    short8 a_h = ldg8(Abh + ((size_t)ntile * 32 + ko) * 128 + l15 * 8);
    short8 a_l = ldg8(Abl + ((size_t)ntile * 32 + ko) * 128 + l15 * 8);
#pragma unroll
    for (int ct = 0; ct < 4; ++ct) {
      short8 w_h = smW[ct * 512 + ko * 16 + l15];
      short8 w_l = smW[2048 + ct * 512 + ko * 16 + l15];
      acc[ct] = mfma16(a_h, w_h, acc[ct]);
      acc[ct] = mfma16(a_h, w_l, acc[ct]);
      acc[ct] = mfma16(a_l, w_h, acc[ct]);
    }
  }
#pragma unroll
  for (int ct = 0; ct < 4; ++ct) {
    float bj = 0.f;
    if (BIASJ) bj = bias[j0 + ct * 16 + l15];
    float s = 0.f, s2 = 0.f;
#pragma unroll
    for (int r = 0; r < 4; ++r) {
      float v = acc[ct][r] + bj;
      int row = i0 + w * 16 + l4 * 4 + r;
      OutF[((size_t)(b * NN + row)) * OD + j0 + ct * 16 + l15] = v;
      if (STATS) { s += v; s2 += v * v; }
    }
    if (STATS) {
      s += __shfl_xor(s, 16); s2 += __shfl_xor(s2, 16);
      s += __shfl_xor(s, 32); s2 += __shfl_xor(s2, 32);
      if (l4 == 0) {
        atomicAdd(&smS[ct * 16 + l15], s);
        atomicAdd(&smS2[ct * 16 + l15], s2);
      }
    }
  }
  if (STATS) {
    __syncthreads();
    if (t < 64) {
      atomicAdd(&sS[j0 + t], smS[t]);
      atomicAdd(&sS2[j0 + t], smS2[t]);
    }
  }
}

// ------- q-projection: one 16-row tile per block, wave w = 16-col ct tile -----------
__global__ __launch_bounds__(256) void k_qproj(const bf16* __restrict__ Xh,
                                               const bf16* __restrict__ Xl,
                                               const bf16* __restrict__ Wh,
                                               const bf16* __restrict__ Wl,
                                               bf16* __restrict__ Qh,
                                               bf16* __restrict__ Ql) {
  __shared__ float scratch[4][320];
  int b = blockIdx.x, ntile = blockIdx.y;
  int t = threadIdx.x, lane = t & 63, w = t >> 6;
  int l15 = lane & 15, l4 = lane >> 4;
  const bf16* Abh = Xh + (size_t)b * NN * C;
  const bf16* Abl = Xl + (size_t)b * NN * C;
  f32x4 acc = {0.f, 0.f, 0.f, 0.f};
#pragma unroll
  for (int ks = 0; ks < 8; ++ks) {
    int ko = ks * 4 + l4;
    short8 a_h = ldg8(Abh + ((size_t)ntile * 32 + ko) * 128 + l15 * 8);
    short8 a_l = ldg8(Abl + ((size_t)ntile * 32 + ko) * 128 + l15 * 8);
    size_t wo = ((size_t)w * 32 + ko) * 128 + l15 * 8;
    short8 w_h = ldg8(Wh + wo);
    short8 w_l = ldg8(Wl + wo);
    acc = mfma16(a_h, w_h, acc);
    acc = mfma16(a_h, w_l, acc);
    acc = mfma16(a_l, w_h, acc);
  }
  float v[4] = {acc[0], acc[1], acc[2], acc[3]};
  size_t tb = ((size_t)ntile * 8 + w * 2) * 128;
  store_tile16(v, Qh + (size_t)b * NN * 64, Ql + (size_t)b * NN * 64, tb,
               scratch[w], lane);
}

// ------- V'[b](c,m) = sum_k W'(c,k) X'[b](m,k) + bias[c]; X-tile LDS-staged ---------
__global__ __launch_bounds__(512, 4) void k_gemm_nm(const bf16* __restrict__ Wh,
                                                    const bf16* __restrict__ Wl,
                                                    const bf16* __restrict__ Xh,
                                                    const bf16* __restrict__ Xl,
                                                    const float* __restrict__ bias,
                                                    bf16* __restrict__ Vh,
                                                    bf16* __restrict__ Vl) {
  __shared__ short8 smX[4096];  // 64KB: hi [0,2048), lo [2048,4096)
  __shared__ float scratch[8][320];
  int b = blockIdx.x, i0 = blockIdx.y * 128, j0 = blockIdx.z * 64;
  int t = threadIdx.x, lane = t & 63, w = t >> 6;
  int l15 = lane & 15, l4 = lane >> 4;
  const bf16* Xbh = Xh + (size_t)b * NN * C;
  const bf16* Xbl = Xl + (size_t)b * NN * C;
  size_t xbase = (size_t)(j0 >> 4) * 4096;
  for (int i = t; i < 2048; i += 512) {
    smX[i]        = ldg8(Xbh + xbase + (size_t)i * 8);
    smX[2048 + i] = ldg8(Xbl + xbase + (size_t)i * 8);
  }
  __syncthreads();
  int ntile = (i0 >> 4) + w;
  f32x4 acc[4];
#pragma unroll
  for (int ct = 0; ct < 4; ++ct) acc[ct] = f32x4{0.f, 0.f, 0.f, 0.f};
#pragma unroll
  for (int ks = 0; ks < 8; ++ks) {
    int ko = ks * 4 + l4;
    short8 a_h = ldg8(Wh + ((size_t)ntile * 32 + ko) * 128 + l15 * 8);
    short8 a_l = ldg8(Wl + ((size_t)ntile * 32 + ko) * 128 + l15 * 8);
#pragma unroll
    for (int ct = 0; ct < 4; ++ct) {
      short8 x_h = smX[ct * 512 + ko * 16 + l15];
      short8 x_l = smX[2048 + ct * 512 + ko * 16 + l15];
      acc[ct] = mfma16(a_h, x_h, acc[ct]);
      acc[ct] = mfma16(a_h, x_l, acc[ct]);
      acc[ct] = mfma16(a_l, x_h, acc[ct]);
    }
  }
  float br[4];
#pragma unroll
  for (int r = 0; r < 4; ++r) br[r] = bias[i0 + w * 16 + l4 * 4 + r];
  bf16* Vbh = Vh + (size_t)b * C * NN;
  bf16* Vbl = Vl + (size_t)b * C * NN;
#pragma unroll
  for (int ct = 0; ct < 4; ++ct) {
    float v[4];
#pragma unroll
    for (int r = 0; r < 4; ++r) v[r] = acc[ct][r] + br[r];
    size_t tb = ((size_t)ntile * (NN >> 3) + ((j0 + ct * 16) >> 3)) * 128;
    store_tile16(v, Vbh, Vbl, tb, scratch[w], lane);
  }
}

// ---------- row softmax stats over E = Q Q^T (online, 2x-unrolled, exact) ----------
__global__ __launch_bounds__(256) void k_rowstats(const bf16* __restrict__ Qh,
                                                  const bf16* __restrict__ Ql,
                                                  float* __restrict__ rm,
                                                  float* __restrict__ irs) {
  __shared__ float redM[4][16], redS[4][16];
  int b = blockIdx.x;
  int t = threadIdx.x, lane = t & 63, w = t >> 6;
  int l15 = lane & 15, l4 = lane >> 4;
  int mt = blockIdx.y;
  const bf16* QHb = Qh + (size_t)b * NN * 64;
  const bf16* QLb = Ql + (size_t)b * NN * 64;
  short8 ah0 = ldg8(QHb + ((size_t)mt * 8 + l4) * 128 + l15 * 8);
  short8 ah1 = ldg8(QHb + ((size_t)mt * 8 + 4 + l4) * 128 + l15 * 8);
  short8 al0 = ldg8(QLb + ((size_t)mt * 8 + l4) * 128 + l15 * 8);
  short8 al1 = ldg8(QLb + ((size_t)mt * 8 + 4 + l4) * 128 + l15 * 8);
  float lmax[4], lsum[4];
#pragma unroll
  for (int r = 0; r < 4; ++r) { lmax[r] = -3.4e38f; lsum[r] = 0.f; }
  for (int nb = w * 32; nb < w * 32 + 32; nb += 2) {
    short8 bh0 = ldg8(QHb + ((size_t)nb * 8 + l4) * 128 + l15 * 8);
    short8 bh1 = ldg8(QHb + ((size_t)nb * 8 + 4 + l4) * 128 + l15 * 8);
    short8 bl0 = ldg8(QLb + ((size_t)nb * 8 + l4) * 128 + l15 * 8);
    short8 bl1 = ldg8(QLb + ((size_t)nb * 8 + 4 + l4) * 128 + l15 * 8);
    short8 ch0 = ldg8(QHb + ((size_t)(nb + 1) * 8 + l4) * 128 + l15 * 8);
    short8 ch1 = ldg8(QHb + ((size_t)(nb + 1) * 8 + 4 + l4) * 128 + l15 * 8);
    short8 cl0 = ldg8(QLb + ((size_t)(nb + 1) * 8 + l4) * 128 + l15 * 8);
    short8 cl1 = ldg8(QLb + ((size_t)(nb + 1) * 8 + 4 + l4) * 128 + l15 * 8);
    f32x4 e1 = {0.f, 0.f, 0.f, 0.f}, e2 = {0.f, 0.f, 0.f, 0.f};
    e1 = mfma16(ah0, bh0, e1); e1 = mfma16(ah1, bh1, e1);
    e1 = mfma16(ah0, bl0, e1); e1 = mfma16(ah1, bl1, e1);
    e1 = mfma16(al0, bh0, e1); e1 = mfma16(al1, bh1, e1);
    e2 = mfma16(ah0, ch0, e2); e2 = mfma16(ah1, ch1, e2);
    e2 = mfma16(ah0, cl0, e2); e2 = mfma16(ah1, cl1, e2);
    e2 = mfma16(al0, ch0, e2); e2 = mfma16(al1, ch1, e2);
#pragma unroll
    for (int r = 0; r < 4; ++r) {
      float nm = fmaxf(lmax[r], fmaxf(e1[r], e2[r]));
      lsum[r] = lsum[r] * __expf(lmax[r] - nm) + __expf(e1[r] - nm) + __expf(e2[r] - nm);
      lmax[r] = nm;
    }
  }
#pragma unroll
  for (int r = 0; r < 4; ++r) {
    for (int mk = 1; mk < 16; mk <<= 1) {
      float om = __shfl_xor(lmax[r], mk, 16);
      float os = __shfl_xor(lsum[r], mk, 16);
      float nm = fmaxf(lmax[r], om);
      lsum[r] = lsum[r] * __expf(lmax[r] - nm) + os * __expf(om - nm);
      lmax[r] = nm;
    }
  }
  if (l15 == 0) {
#pragma unroll
    for (int r = 0; r < 4; ++r) {
      redM[w][l4 * 4 + r] = lmax[r];
      redS[w][l4 * 4 + r] = lsum[r];
    }
  }
  __syncthreads();
  if (t < 16) {
    float m = redM[0][t];
    m = fmaxf(m, redM[1][t]); m = fmaxf(m, redM[2][t]); m = fmaxf(m, redM[3][t]);
    float s = 0.f;
#pragma unroll
    for (int w2 = 0; w2 < 4; ++w2) s += redS[w2][t] * __expf(redM[w2][t] - m);
    rm[b * NN + mt * 16 + t] = m;
    irs[b * NN + mt * 16 + t] = 1.0f / s;
  }
}

// ---------------- fused attention: D' = X - (V att)/(1e-9+colsum), swizzled out ------
// R14 known-good structure (71us): 128-m steps, 16 raw barriers, batch V-issue,
// 64 VGPR / 44.5KB LDS -> 2 resident blocks/CU convoy. V hi/lo (R11). NO setprio
// (R9). NO E-prefetch (R13 spill). NO 256-m step (R15: occupancy+pipeline loss).
__global__ __launch_bounds__(512, 4) void k_attnY(const bf16* __restrict__ QH,
                                                  const bf16* __restrict__ QL,
                                                  const bf16* __restrict__ VH,
                                                  const bf16* __restrict__ VL,
                                                  const float* __restrict__ rm,
                                                  const float* __restrict__ irs,
                                                  const bf16* __restrict__ XH,
                                                  const bf16* __restrict__ XL,
                                                  bf16* __restrict__ DH,
                                                  bf16* __restrict__ DL) {
  __shared__ bf16 Pb[2][32 * 136];
  __shared__ float rmL[2048], irL[2048];
  __shared__ float colLds[32];
  __shared__ float scratch[8][320];
  int bid = blockIdx.x;
  int b = bid & 7, n0 = (bid >> 3) * 32;
  int t = threadIdx.x, lane = t & 63, w = t >> 6;
  int l15 = lane & 15, l4 = lane >> 4;
  int nt = w >> 2, pp = w & 3;
  const bf16* QHb = QH + (size_t)b * NN * 64;
  const bf16* QLb = QL + (size_t)b * NN * 64;
  const bf16* VHb = VH + (size_t)b * C * NN;
  const bf16* VLb = VL + (size_t)b * C * NN;
  for (int i = t; i < NN; i += 512) {
    rmL[i] = rm[b * NN + i];
    irL[i] = irs[b * NN + i];
  }
  if (t < 32) colLds[t] = 0.f;
  int ntq = (n0 >> 4) + nt;
  short8 qh0 = ldg8(QHb + ((size_t)ntq * 8 + l4) * 128 + l15 * 8);
  short8 qh1 = ldg8(QHb + ((size_t)ntq * 8 + 4 + l4) * 128 + l15 * 8);
  short8 ql0 = ldg8(QLb + ((size_t)ntq * 8 + l4) * 128 + l15 * 8);
  short8 ql1 = ldg8(QLb + ((size_t)ntq * 8 + 4 + l4) * 128 + l15 * 8);
  f32x4 zero = {0.f, 0.f, 0.f, 0.f};
  f32x4 acc[2][2];
#pragma unroll
  for (int a = 0; a < 2; ++a)
#pragma unroll
    for (int ct = 0; ct < 2; ++ct) acc[a][ct] = zero;
  float cac[4] = {0.f, 0.f, 0.f, 0.f};
  __syncthreads();
  for (int s = 0; s < 16; ++s) {
    bf16* pbw = Pb[s & 1];
    // ---- E phase: two 16x16 tiles ----
#pragma unroll
    for (int sub = 0; sub < 2; ++sub) {
      int mt8 = pp * 2 + sub;
      int gmt = s * 8 + mt8;
      short8 bh0 = ldg8(QHb + ((size_t)gmt * 8 + l4) * 128 + l15 * 8);
      short8 bh1 = ldg8(QHb + ((size_t)gmt * 8 + 4 + l4) * 128 + l15 * 8);
      short8 bl0 = ldg8(QLb + ((size_t)gmt * 8 + l4) * 128 + l15 * 8);
      short8 bl1 = ldg8(QLb + ((size_t)gmt * 8 + 4 + l4) * 128 + l15 * 8);
      f32x4 eA = zero, eB = zero;
      eA = mfma16(qh0, bh0, eA); eB = mfma16(qh1, bh1, eB);
      eA = mfma16(qh0, bl0, eA); eB = mfma16(qh1, bl1, eB);
      eA = mfma16(ql0, bh0, eA); eB = mfma16(ql1, bh1, eB);
      float rmv = rmL[gmt * 16 + l15], iv = irL[gmt * 16 + l15];
      int blk = nt * 16 + mt8 * 2 + (l15 >> 3);
#pragma unroll
      for (int r = 0; r < 4; ++r) {
        float p = __expf(eA[r] + eB[r] - rmv) * iv;
        bf16 ph = __float2bfloat16(p);
        cac[r] += __bfloat162float(ph);
        pbw[blk * 136 + (l4 * 4 + r) * 8 + (l15 & 7)] = ph;
      }
    }
    // ---- prefetch V kc 0,1 (stays in flight across raw barrier) ----
    short8 vhA[2][2], vlA[2][2];
#pragma unroll
    for (int kc = 0; kc < 2; ++kc)
#pragma unroll
      for (int ct = 0; ct < 2; ++ct) {
        size_t vo = ((size_t)(w * 2 + ct) * 256 + s * 16 + kc * 4 + l4) * 128 + l15 * 8;
        vhA[kc][ct] = ldg8(VHb + vo);
        vlA[kc][ct] = ldg8(VLb + vo);
      }
    asm volatile("s_waitcnt lgkmcnt(0)" ::: "memory");
    __builtin_amdgcn_sched_barrier(0);
    __builtin_amdgcn_s_barrier();
    // ---- issue V kc 2,3, then PV ----
    short8 vhB[2][2], vlB[2][2];
#pragma unroll
    for (int kc = 0; kc < 2; ++kc)
#pragma unroll
      for (int ct = 0; ct < 2; ++ct) {
        size_t vo = ((size_t)(w * 2 + ct) * 256 + s * 16 + (kc + 2) * 4 + l4) * 128 + l15 * 8;
        vhB[kc][ct] = ldg8(VHb + vo);
        vlB[kc][ct] = ldg8(VLb + vo);
      }
#pragma unroll
    for (int kc = 0; kc < 2; ++kc) {
      short8 pa0 = *reinterpret_cast<const short8*>(&pbw[(kc * 4 + l4) * 136 + l15 * 8]);
      short8 pa1 = *reinterpret_cast<const short8*>(&pbw[(16 + kc * 4 + l4) * 136 + l15 * 8]);
#pragma unroll
      for (int ct = 0; ct < 2; ++ct) {
        acc[0][ct] = mfma16(pa0, vhA[kc][ct], acc[0][ct]);
        acc[0][ct] = mfma16(pa0, vlA[kc][ct], acc[0][ct]);
        acc[1][ct] = mfma16(pa1, vhA[kc][ct], acc[1][ct]);
        acc[1][ct] = mfma16(pa1, vlA[kc][ct], acc[1][ct]);
      }
    }
#pragma unroll
    for (int kc = 0; kc < 2; ++kc) {
      short8 pa0 = *reinterpret_cast<const short8*>(&pbw[((kc + 2) * 4 + l4) * 136 + l15 * 8]);
      short8 pa1 = *reinterpret_cast<const short8*>(&pbw[(16 + (kc + 2) * 4 + l4) * 136 + l15 * 8]);
#pragma unroll
      for (int ct = 0; ct < 2; ++ct) {
        acc[0][ct] = mfma16(pa0, vhB[kc][ct], acc[0][ct]);
        acc[0][ct] = mfma16(pa0, vlB[kc][ct], acc[0][ct]);
        acc[1][ct] = mfma16(pa1, vhB[kc][ct], acc[1][ct]);
        acc[1][ct] = mfma16(pa1, vlB[kc][ct], acc[1][ct]);
      }
    }
  }
  // colsum: reduce over 16 m-lanes; 4 p-waves per nt combine via LDS atomics
#pragma unroll
  for (int r = 0; r < 4; ++r) {
    float v2 = cac[r];
    v2 += __shfl_xor(v2, 1, 16); v2 += __shfl_xor(v2, 2, 16);
    v2 += __shfl_xor(v2, 4, 16); v2 += __shfl_xor(v2, 8, 16);
    if (l15 == 0) atomicAdd(&colLds[nt * 16 + l4 * 4 + r], v2);
  }
  __syncthreads();
  if (t < 32) colLds[t] = 1.0f / (1e-9f + colLds[t]);
  __syncthreads();
  const bf16* XHb = XH + (size_t)b * NN * C;
  const bf16* XLb = XL + (size_t)b * NN * C;
  bf16* DHb = DH + (size_t)b * NN * C;
  bf16* DLb = DL + (size_t)b * NN * C;
#pragma unroll
  for (int a = 0; a < 2; ++a) {
#pragma unroll
    for (int ct = 0; ct < 2; ++ct) {
      float d[4];
      int cidx = w * 32 + ct * 16 + l15;
#pragma unroll
      for (int r = 0; r < 4; ++r) {
        int n = n0 + a * 16 + l4 * 4 + r;
        size_t off = ((size_t)(n >> 4) * 32 + (cidx >> 3)) * 128 + (n & 15) * 8 + (cidx & 7);
        float xv = __bfloat162float(XHb[off]) + __bfloat162float(XLb[off]);
        d[r] = xv - acc[a][ct][r] * colLds[a * 16 + l4 * 4 + r];
      }
      size_t tb = ((size_t)((n0 >> 4) + a) * 32 + ((w * 32 + ct * 16) >> 3)) * 128;
      store_tile16(d, DHb, DLb, tb, scratch[w], lane);
    }
  }
}

// -------- BN + ReLU (+ residual + out); x canonical as hi/lo pair --------
template <bool RES>
__global__ __launch_bounds__(256) void k_bnrelu(const float* __restrict__ Tt,
                                                const float* __restrict__ sS,
                                                const float* __restrict__ sS2,
                                                const float* __restrict__ g,
                                                const float* __restrict__ bb,
                                                bf16* __restrict__ Xh,
                                                bf16* __restrict__ Xl,
                                                float* __restrict__ outp, int Loff) {
  __shared__ float vb[16][257];
  int b = blockIdx.x, n0 = blockIdx.y * 16;
  int c = threadIdx.x;
  float cnt = (float)(BB * NN);
  float mean = sS[c] / cnt;
  float var = fmaxf(sS2[c] / cnt - mean * mean, 0.f);
  float sc = g[c] * rsqrtf(var + 1e-5f);
  float sh = bb[c] - mean * sc;
#pragma unroll
  for (int i = 0; i < 16; ++i) {
    int n = n0 + i;
    size_t idx = ((size_t)(b * NN + n)) * C + c;
    float v = Tt[idx] * sc + sh;
    v = fmaxf(v, 0.f);
    size_t off = (size_t)b * NN * C +
                 ((size_t)(n >> 4) * 32 + (c >> 3)) * 128 + (n & 15) * 8 + (c & 7);
    if (RES) v += __bfloat162float(Xh[off]) + __bfloat162float(Xl[off]);
    bf16 h, l;
    split2(v, h, l);
    Xh[off] = h;
    Xl[off] = l;
    if (RES) vb[i][c] = v;
  }
  if (RES) {
    __syncthreads();
    int nl = threadIdx.x & 15, cb = threadIdx.x >> 4;
#pragma unroll
    for (int j = 0; j < 16; ++j) {
      int cc = cb + j * 16;
      outp[((size_t)(b * 1024 + Loff + cc)) * NN + n0 + nl] = vb[nl][cc];
    }
  }
}

extern "C" void kernel_launch(void* const* d_in, const int* in_sizes, int n_in,
                              void* d_out, int out_size, void* d_ws, size_t ws_size,
                              hipStream_t stream) {
  const float* x       = (const float*)d_in[0];
  const float* conv1_w = (const float*)d_in[1];
  const float* conv2_w = (const float*)d_in[2];
  const float* bn1_g   = (const float*)d_in[3];
  const float* bn1_b   = (const float*)d_in[4];
  const float* bn2_g   = (const float*)d_in[5];
  const float* bn2_b   = (const float*)d_in[6];
  const float* wqk     = (const float*)d_in[7];
  const float* wv      = (const float*)d_in[8];
  const float* bv      = (const float*)d_in[9];
  const float* wt      = (const float*)d_in[10];
  const float* bt      = (const float*)d_in[11];
  const float* sg      = (const float*)d_in[12];
  const float* sb      = (const float*)d_in[13];
  float* out = (float*)d_out;

  char* p = (char*)d_ws;
  auto take = [&](size_t n) { char* r = p; p += n; return r; };
  bf16* WB1h = (bf16*)take(131072);
  bf16* WB1l = (bf16*)take(131072);
  bf16* WB2h = (bf16*)take(131072);
  bf16* WB2l = (bf16*)take(131072);
  bf16* WBQh = (bf16*)take(131072);
  bf16* WBQl = (bf16*)take(131072);
  bf16* WBVh = (bf16*)take(524288);
  bf16* WBVl = (bf16*)take(524288);
  bf16* WBTh = (bf16*)take(524288);
  bf16* WBTl = (bf16*)take(524288);
  bf16* XTh  = (bf16*)take(8388608);
  bf16* XTl  = (bf16*)take(8388608);
  bf16* QTh  = (bf16*)take(2097152);
  bf16* QTl  = (bf16*)take(2097152);
  bf16* VBh  = (bf16*)take(8388608);
  bf16* VBl  = (bf16*)take(8388608);
  float* TT  = (float*)VBh;  // alias: t-GEMM output written after attnY consumed V
  bf16* DTh  = (bf16*)take(8388608);
  bf16* DTl  = (bf16*)take(8388608);
  float* RM   = (float*)take(65536);
  float* IRS  = (float*)take(65536);
  float* STAT = (float*)take(12288);

  hipMemsetAsync(STAT, 0, 6 * 512 * sizeof(float), stream);
  k_cvtW5<<<352, 256, 0, stream>>>(conv1_w, conv2_w, wqk, wv, wt,
                                   WB1h, WB1l, WB2h, WB2l, WBQh, WBQl,
                                   WBVh, WBVl, WBTh, WBTl);
  k_tin<<<dim3(32, 4, 8), 256, 0, stream>>>(x, XTh, XTl);

  // conv1 + bn1 + relu   (TT aliases VB, safe — V not yet used)
  k_gemm_tr<false, true><<<dim3(8, 16, 4), 512, 0, stream>>>(
      XTh, XTl, WB1h, WB1l, nullptr, TT, 256, STAT + 0, STAT + 256);
  k_bnrelu<false><<<dim3(8, 128), 256, 0, stream>>>(TT, STAT + 0, STAT + 256, bn1_g, bn1_b,
                                                    XTh, XTl, nullptr, 0);

  // conv2 + bn2 + relu
  k_gemm_tr<false, true><<<dim3(8, 16, 4), 512, 0, stream>>>(
      XTh, XTl, WB2h, WB2l, nullptr, TT, 256, STAT + 512, STAT + 768);
  k_bnrelu<false><<<dim3(8, 128), 256, 0, stream>>>(TT, STAT + 512, STAT + 768, bn2_g, bn2_b,
                                                    XTh, XTl, nullptr, 0);

  for (int L = 0; L < 4; ++L) {
    float* ST = STAT + (2 + L) * 512;
    // q projection -> Q' swizzled [B], rows=N, K=64
    k_qproj<<<dim3(8, 128), 256, 0, stream>>>(XTh, XTl, WBQh + L * 16384,
                                              WBQl + L * 16384, QTh, QTl);
    // v projection -> V' swizzled [B], rows=C, K=N (hi+lo; X-tile LDS-staged)
    k_gemm_nm<<<dim3(8, 2, 32), 512, 0, stream>>>(WBVh + L * 65536, WBVl + L * 65536,
                                                  XTh, XTl, bv + L * 256, VBh, VBl);
    // softmax row stats (online, 2x-unrolled)
    k_rowstats<<<dim3(8, 128), 256, 0, stream>>>(QTh, QTl, RM, IRS);
    // fused E + softmax (P once) + renorm + V-apply + subtract -> D' swizzled
    k_attnY<<<512, 512, 0, stream>>>(QTh, QTl, VBh, VBl, RM, IRS, XTh, XTl, DTh, DTl);
    // t projection + stats (TT aliases VB — V fully consumed by attnY above)
    k_gemm_tr<true, true><<<dim3(8, 16, 4), 512, 0, stream>>>(
        DTh, DTl, WBTh + L * 65536, WBTl + L * 65536, bt + L * 256, TT, 256, ST, ST + 256);
    // bn + relu + residual + output slice (bnfin fused)
    k_bnrelu<true><<<dim3(8, 128), 256, 0, stream>>>(TT, ST, ST + 256, sg + L * 256,
                                                     sb + L * 256, XTh, XTl, out,
                                                     L * 256);
  }
}